// Round 1
// baseline (15410.225 us; speedup 1.0000x reference)
//
#include <hip/hip_runtime.h>
#include <math.h>

#define HID 100
#define SEQT 10
#define NOUT 5
#define BTILE 64      // batch elements per block
#define NTHR 256      // 4 waves
#define JPER 25       // output neurons per wave
#define JC 5          // chunk size (accumulators = 4*JC)
#define NCHUNK 5      // JPER / JC

// packed weight sizes (floats)
#define P0_FLOATS (20 * HID * 15)   // 30000: L0 hh, per-chunk column-major
#define P1_FLOATS (20 * HID * 30)   // 60000: L1 ih+hh, per-chunk column-major

__device__ __forceinline__ float sigm(float x) {
    float e = __expf(-x);
    return __builtin_amdgcn_rcpf(1.0f + e);
}
__device__ __forceinline__ float tanh_fast(float x) {
    float e = __expf(-2.0f * x);
    return fmaf(2.0f, __builtin_amdgcn_rcpf(1.0f + e), -1.0f);
}

// Repack weights so that for chunk c (5 output neurons) and column k, all
// weights needed in one k-step are contiguous -> single wide s_load stream.
__global__ __launch_bounds__(256) void prep_kernel(
        const float* __restrict__ Whh0,
        const float* __restrict__ Wih1,
        const float* __restrict__ Whh1,
        float* __restrict__ ws) {
    int idx = blockIdx.x * blockDim.x + threadIdx.x;
    int stride = gridDim.x * blockDim.x;
    // L0: ws[(chunk*HID + k)*15 + g*5 + u] = Whh0[(g*100 + chunk*5 + u)*100 + k]
    for (int i = idx; i < P0_FLOATS; i += stride) {
        int s = i % 15; int rest = i / 15;
        int k = rest % HID; int chunk = rest / HID;
        int g = s / JC, u = s % JC;
        ws[i] = Whh0[(g * HID + chunk * JC + u) * HID + k];
    }
    // L1: [ih_r x5, ih_z x5, ih_n x5, hh_r x5, hh_z x5, hh_n x5] per (chunk,k)
    float* w1 = ws + P0_FLOATS;
    for (int i = idx; i < P1_FLOATS; i += stride) {
        int s = i % 30; int rest = i / 30;
        int k = rest % HID; int chunk = rest / HID;
        int m = s / 15;                 // 0 = ih, 1 = hh
        int g = (s % 15) / JC, u = s % JC;
        const float* src = m ? Whh1 : Wih1;
        w1[i] = src[(g * HID + chunk * JC + u) * HID + k];
    }
}

template <bool PACKED>
__global__ __launch_bounds__(NTHR, 2)
void gru_main(const float* __restrict__ x,
              const float* __restrict__ Wih0,
              const float* __restrict__ bih0, const float* __restrict__ bhh0,
              const float* __restrict__ bih1, const float* __restrict__ bhh1,
              const float* __restrict__ Wlin, const float* __restrict__ blin,
              const float* __restrict__ P0,    // packed L0 or Whh0
              const float* __restrict__ P1,    // packed L1 or Wih1
              const float* __restrict__ P1b,   // unused or Whh1
              float* __restrict__ out) {
    __shared__ float h1s[HID][BTILE];
    __shared__ float h2s[HID][BTILE];
    __shared__ float seq[SEQT + NOUT][BTILE];

    const int tid = threadIdx.x;
    const int b = tid & (BTILE - 1);
    const int q = tid >> 6;                               // wave id 0..3
    const int chunkbase = __builtin_amdgcn_readfirstlane(q * NCHUNK);
    const int blockStart = blockIdx.x * BTILE;

    // stage x -> seq (coalesced)
    for (int i = tid; i < BTILE * SEQT; i += NTHR) {
        float v = x[blockStart * SEQT + i];
        int bb = i / SEQT;
        int tt = i - bb * SEQT;
        seq[tt][bb] = v;
    }
    __syncthreads();

    for (int it = 0; it < NOUT; ++it) {
        // reset hidden states
        for (int i = tid; i < HID * BTILE; i += NTHR) {
            ((float*)h1s)[i] = 0.0f;
            ((float*)h2s)[i] = 0.0f;
        }
        __syncthreads();

        for (int t = 0; t < SEQT; ++t) {
            const float xt = seq[it + t][b];
            float hnew[JPER];

            // ================= layer 0 (input = scalar xt) =================
            #pragma unroll
            for (int c = 0; c < NCHUNK; ++c) {
                const int chunkid = chunkbase + c;
                const int j0 = chunkid * JC;
                float ar[JC], az[JC], ain[JC], ahn[JC];
                #pragma unroll
                for (int u = 0; u < JC; ++u) {
                    int j = j0 + u;
                    ar[u]  = fmaf(xt, Wih0[j],           bih0[j] + bhh0[j]);
                    az[u]  = fmaf(xt, Wih0[HID + j],     bih0[HID + j] + bhh0[HID + j]);
                    ain[u] = fmaf(xt, Wih0[2 * HID + j], bih0[2 * HID + j]);
                    ahn[u] = bhh0[2 * HID + j];
                }
                if (t > 0) {
                    for (int k = 0; k < HID; ++k) {
                        const float hk = h1s[k][b];
                        if constexpr (PACKED) {
                            const float* w = P0 + (chunkid * HID + k) * 15;
                            #pragma unroll
                            for (int u = 0; u < JC; ++u) {
                                ar[u]  = fmaf(hk, w[u],          ar[u]);
                                az[u]  = fmaf(hk, w[JC + u],     az[u]);
                                ahn[u] = fmaf(hk, w[2 * JC + u], ahn[u]);
                            }
                        } else {
                            #pragma unroll
                            for (int u = 0; u < JC; ++u) {
                                int j = j0 + u;
                                ar[u]  = fmaf(hk, P0[j * HID + k],             ar[u]);
                                az[u]  = fmaf(hk, P0[(HID + j) * HID + k],     az[u]);
                                ahn[u] = fmaf(hk, P0[(2 * HID + j) * HID + k], ahn[u]);
                            }
                        }
                    }
                }
                #pragma unroll
                for (int u = 0; u < JC; ++u) {
                    float r = sigm(ar[u]);
                    float z = sigm(az[u]);
                    float n = tanh_fast(fmaf(r, ahn[u], ain[u]));
                    float hold = (t > 0) ? h1s[j0 + u][b] : 0.0f;
                    hnew[c * JC + u] = fmaf(z, hold - n, n);   // (1-z)n + z h
                }
            }
            __syncthreads();
            #pragma unroll
            for (int u = 0; u < JPER; ++u) h1s[chunkbase * JC + u][b] = hnew[u];
            __syncthreads();

            // ================= layer 1 (input = h1, state = h2) =================
            #pragma unroll
            for (int c = 0; c < NCHUNK; ++c) {
                const int chunkid = chunkbase + c;
                const int j0 = chunkid * JC;
                float ar[JC], az[JC], ain[JC], ahn[JC];
                #pragma unroll
                for (int u = 0; u < JC; ++u) {
                    int j = j0 + u;
                    ar[u]  = bih1[j] + bhh1[j];
                    az[u]  = bih1[HID + j] + bhh1[HID + j];
                    ain[u] = bih1[2 * HID + j];
                    ahn[u] = bhh1[2 * HID + j];
                }
                if (t > 0) {
                    for (int k = 0; k < HID; ++k) {
                        const float h1k = h1s[k][b];
                        const float h2k = h2s[k][b];
                        if constexpr (PACKED) {
                            const float* w = P1 + (chunkid * HID + k) * 30;
                            #pragma unroll
                            for (int u = 0; u < JC; ++u) {
                                ar[u]  = fmaf(h1k, w[u],          ar[u]);
                                az[u]  = fmaf(h1k, w[JC + u],     az[u]);
                                ain[u] = fmaf(h1k, w[2 * JC + u], ain[u]);
                                ar[u]  = fmaf(h2k, w[3 * JC + u], ar[u]);
                                az[u]  = fmaf(h2k, w[4 * JC + u], az[u]);
                                ahn[u] = fmaf(h2k, w[5 * JC + u], ahn[u]);
                            }
                        } else {
                            #pragma unroll
                            for (int u = 0; u < JC; ++u) {
                                int j = j0 + u;
                                ar[u]  = fmaf(h1k, P1[j * HID + k],              ar[u]);
                                az[u]  = fmaf(h1k, P1[(HID + j) * HID + k],      az[u]);
                                ain[u] = fmaf(h1k, P1[(2 * HID + j) * HID + k],  ain[u]);
                                ar[u]  = fmaf(h2k, P1b[j * HID + k],             ar[u]);
                                az[u]  = fmaf(h2k, P1b[(HID + j) * HID + k],     az[u]);
                                ahn[u] = fmaf(h2k, P1b[(2 * HID + j) * HID + k], ahn[u]);
                            }
                        }
                    }
                } else {
                    // t == 0: h2 == 0, only the ih matmul contributes
                    for (int k = 0; k < HID; ++k) {
                        const float h1k = h1s[k][b];
                        if constexpr (PACKED) {
                            const float* w = P1 + (chunkid * HID + k) * 30;
                            #pragma unroll
                            for (int u = 0; u < JC; ++u) {
                                ar[u]  = fmaf(h1k, w[u],          ar[u]);
                                az[u]  = fmaf(h1k, w[JC + u],     az[u]);
                                ain[u] = fmaf(h1k, w[2 * JC + u], ain[u]);
                            }
                        } else {
                            #pragma unroll
                            for (int u = 0; u < JC; ++u) {
                                int j = j0 + u;
                                ar[u]  = fmaf(h1k, P1[j * HID + k],             ar[u]);
                                az[u]  = fmaf(h1k, P1[(HID + j) * HID + k],     az[u]);
                                ain[u] = fmaf(h1k, P1[(2 * HID + j) * HID + k], ain[u]);
                            }
                        }
                    }
                }
                #pragma unroll
                for (int u = 0; u < JC; ++u) {
                    float r = sigm(ar[u]);
                    float z = sigm(az[u]);
                    float n = tanh_fast(fmaf(r, ahn[u], ain[u]));
                    float hold = (t > 0) ? h2s[j0 + u][b] : 0.0f;
                    hnew[c * JC + u] = fmaf(z, hold - n, n);
                }
            }
            __syncthreads();
            #pragma unroll
            for (int u = 0; u < JPER; ++u) h2s[chunkbase * JC + u][b] = hnew[u];
            __syncthreads();
        }

        // output projection: ret = h2(t=9) . Wlin + blin
        if (q == 0) {
            float acc = blin[0];
            for (int k = 0; k < HID; ++k)
                acc = fmaf(h2s[k][b], Wlin[k], acc);
            out[(blockStart + b) * NOUT + it] = acc;
            seq[SEQT + it][b] = acc;
        }
        __syncthreads();
    }
}

extern "C" void kernel_launch(void* const* d_in, const int* in_sizes, int n_in,
                              void* d_out, int out_size, void* d_ws, size_t ws_size,
                              hipStream_t stream) {
    const float* x    = (const float*)d_in[0];
    const float* Wih0 = (const float*)d_in[1];
    const float* Whh0 = (const float*)d_in[2];
    const float* bih0 = (const float*)d_in[3];
    const float* bhh0 = (const float*)d_in[4];
    const float* Wih1 = (const float*)d_in[5];
    const float* Whh1 = (const float*)d_in[6];
    const float* bih1 = (const float*)d_in[7];
    const float* bhh1 = (const float*)d_in[8];
    const float* Wlin = (const float*)d_in[9];
    const float* blin = (const float*)d_in[10];
    float* out = (float*)d_out;

    const int B = in_sizes[0] / SEQT;
    const int nblocks = B / BTILE;

    const size_t packBytes = (size_t)(P0_FLOATS + P1_FLOATS) * sizeof(float);
    if (ws_size >= packBytes) {
        float* ws = (float*)d_ws;
        prep_kernel<<<90, 256, 0, stream>>>(Whh0, Wih1, Whh1, ws);
        gru_main<true><<<nblocks, NTHR, 0, stream>>>(
            x, Wih0, bih0, bhh0, bih1, bhh1, Wlin, blin,
            ws, ws + P0_FLOATS, nullptr, out);
    } else {
        gru_main<false><<<nblocks, NTHR, 0, stream>>>(
            x, Wih0, bih0, bhh0, bih1, bhh1, Wlin, blin,
            Whh0, Wih1, Whh1, out);
    }
}

// Round 2
// 15150.797 us; speedup vs baseline: 1.0171x; 1.0171x over previous
//
#include <hip/hip_runtime.h>
#include <math.h>

#define HID 100
#define SEQT 10
#define NOUT 5
#define BTILE 64      // batch elements per block
#define NTHR 256      // 4 waves
#define JPER 25       // output neurons per wave
#define JC 5          // chunk size (accumulators = 4*JC)
#define NCHUNK 5      // JPER / JC

// packed weight sizes (floats)
#define P0_FLOATS (20 * HID * 15)   // 30000: L0 hh, per-(chunk,k) contiguous
#define P1_FLOATS (20 * HID * 30)   // 60000: L1 ih+hh, per-(chunk,k) contiguous
#define CB_FLOATS (2 * 4 * HID)     // 800: fused biases, layer0 then layer1

__device__ __forceinline__ float sigm(float x) {
    float e = __expf(-x);
    return __builtin_amdgcn_rcpf(1.0f + e);
}
__device__ __forceinline__ float tanh_fast(float x) {
    float e = __expf(-2.0f * x);
    return fmaf(2.0f, __builtin_amdgcn_rcpf(1.0f + e), -1.0f);
}

// Repack weights so that for chunk c (5 output neurons) and column k, all
// weights needed in one k-step are contiguous -> single wide s_load stream.
// Also pre-fuse biases: [br=bih+bhh, bz=bih+bhh, bin=bih_n, bhn=bhh_n].
__global__ __launch_bounds__(256) void prep_kernel(
        const float* __restrict__ Whh0,
        const float* __restrict__ Wih1,
        const float* __restrict__ Whh1,
        const float* __restrict__ bih0, const float* __restrict__ bhh0,
        const float* __restrict__ bih1, const float* __restrict__ bhh1,
        float* __restrict__ ws) {
    int idx = blockIdx.x * blockDim.x + threadIdx.x;
    int stride = gridDim.x * blockDim.x;
    // L0: ws[(chunk*HID + k)*15 + g*5 + u] = Whh0[(g*100 + chunk*5 + u)*100 + k]
    for (int i = idx; i < P0_FLOATS; i += stride) {
        int s = i % 15; int rest = i / 15;
        int k = rest % HID; int chunk = rest / HID;
        int g = s / JC, u = s % JC;
        ws[i] = Whh0[(g * HID + chunk * JC + u) * HID + k];
    }
    // L1: [ih_r x5, ih_z x5, ih_n x5, hh_r x5, hh_z x5, hh_n x5] per (chunk,k)
    float* w1 = ws + P0_FLOATS;
    for (int i = idx; i < P1_FLOATS; i += stride) {
        int s = i % 30; int rest = i / 30;
        int k = rest % HID; int chunk = rest / HID;
        int m = s / 15;                 // 0 = ih, 1 = hh
        int g = (s % 15) / JC, u = s % JC;
        const float* src = m ? Whh1 : Wih1;
        w1[i] = src[(g * HID + chunk * JC + u) * HID + k];
    }
    // fused biases
    float* cb = ws + P0_FLOATS + P1_FLOATS;
    for (int i = idx; i < CB_FLOATS; i += stride) {
        int which = i / (4 * HID);
        int r = i % (4 * HID);
        int g = r / HID; int j = r % HID;
        const float* bi = which ? bih1 : bih0;
        const float* bh = which ? bhh1 : bhh0;
        float v;
        if (g == 0)      v = bi[j] + bh[j];
        else if (g == 1) v = bi[HID + j] + bh[HID + j];
        else if (g == 2) v = bi[2 * HID + j];
        else             v = bh[2 * HID + j];
        cb[i] = v;
    }
}

template <bool PACKED>
__global__ __launch_bounds__(NTHR, 3)
void gru_main(const float* __restrict__ x,
              const float* __restrict__ Wih0,
              const float* __restrict__ bih0, const float* __restrict__ bhh0,
              const float* __restrict__ bih1, const float* __restrict__ bhh1,
              const float* __restrict__ Wlin, const float* __restrict__ blin,
              const float* __restrict__ P0,    // packed L0 or Whh0
              const float* __restrict__ P1,    // packed L1 or Wih1
              const float* __restrict__ P1b,   // CB (packed) or Whh1
              float* __restrict__ out) {
    __shared__ float h1s[HID][BTILE];   // 25.6 KB
    __shared__ float h2s[HID][BTILE];   // 25.6 KB
    __shared__ float rets[NOUT][BTILE]; // 1.25 KB  -> 52.5 KB total: 3 blocks/CU

    const int tid = threadIdx.x;
    const int b = tid & (BTILE - 1);
    const int q = tid >> 6;                               // wave id 0..3
    const int chunkbase = __builtin_amdgcn_readfirstlane(q * NCHUNK);
    const int jbase = chunkbase * JC;
    const int blockStart = blockIdx.x * BTILE;

    const float* CB0 = PACKED ? P1b : nullptr;
    const float* CB1 = PACKED ? (P1b + 4 * HID) : nullptr;

    // x -> registers (one-time, 40B/lane)
    float xr[SEQT];
    {
        const float* xp = x + (size_t)(blockStart + b) * SEQT;
        #pragma unroll
        for (int i = 0; i < SEQT; ++i) xr[i] = xp[i];
    }

    for (int it = 0; it < NOUT; ++it) {
        for (int t = 0; t < SEQT; ++t) {
            // xt = vals[it + t]  (uniform select; no runtime reg indexing)
            float xt;
            {
                const int s = it + t;
                if (s < SEQT) {
                    float v = xr[0];
                    #pragma unroll
                    for (int i = 1; i < SEQT; ++i) if (s == i) v = xr[i];
                    xt = v;
                } else {
                    xt = rets[s - SEQT][b];
                }
            }
            float hnew[JPER];

            // ================= layer 0 (input = scalar xt) =================
            #pragma unroll
            for (int c = 0; c < NCHUNK; ++c) {
                const int chunkid = chunkbase + c;
                const int j0 = chunkid * JC;
                float ar[JC], az[JC], ain[JC], ahn[JC];
                #pragma unroll
                for (int u = 0; u < JC; ++u) {
                    int j = j0 + u;
                    if constexpr (PACKED) {
                        ar[u]  = fmaf(xt, Wih0[j],           CB0[j]);
                        az[u]  = fmaf(xt, Wih0[HID + j],     CB0[HID + j]);
                        ain[u] = fmaf(xt, Wih0[2 * HID + j], CB0[2 * HID + j]);
                        ahn[u] = CB0[3 * HID + j];
                    } else {
                        ar[u]  = fmaf(xt, Wih0[j],           bih0[j] + bhh0[j]);
                        az[u]  = fmaf(xt, Wih0[HID + j],     bih0[HID + j] + bhh0[HID + j]);
                        ain[u] = fmaf(xt, Wih0[2 * HID + j], bih0[2 * HID + j]);
                        ahn[u] = bhh0[2 * HID + j];
                    }
                }
                if (t > 0) {
                    for (int k = 0; k < HID; ++k) {
                        const float hk = h1s[k][b];
                        if constexpr (PACKED) {
                            const float* w = P0 + (chunkid * HID + k) * 15;
                            #pragma unroll
                            for (int u = 0; u < JC; ++u) {
                                ar[u]  = fmaf(hk, w[u],          ar[u]);
                                az[u]  = fmaf(hk, w[JC + u],     az[u]);
                                ahn[u] = fmaf(hk, w[2 * JC + u], ahn[u]);
                            }
                        } else {
                            #pragma unroll
                            for (int u = 0; u < JC; ++u) {
                                int j = j0 + u;
                                ar[u]  = fmaf(hk, P0[j * HID + k],             ar[u]);
                                az[u]  = fmaf(hk, P0[(HID + j) * HID + k],     az[u]);
                                ahn[u] = fmaf(hk, P0[(2 * HID + j) * HID + k], ahn[u]);
                            }
                        }
                    }
                }
                #pragma unroll
                for (int u = 0; u < JC; ++u) {
                    float r = sigm(ar[u]);
                    float z = sigm(az[u]);
                    float n = tanh_fast(fmaf(r, ahn[u], ain[u]));
                    float hold = (t > 0) ? h1s[j0 + u][b] : 0.0f;
                    hnew[c * JC + u] = fmaf(z, hold - n, n);   // (1-z)n + z h
                }
            }
            __syncthreads();
            #pragma unroll
            for (int u = 0; u < JPER; ++u) h1s[jbase + u][b] = hnew[u];
            __syncthreads();

            // ================= layer 1 (input = h1, state = h2) =================
            #pragma unroll
            for (int c = 0; c < NCHUNK; ++c) {
                const int chunkid = chunkbase + c;
                const int j0 = chunkid * JC;
                float ar[JC], az[JC], ain[JC], ahn[JC];
                #pragma unroll
                for (int u = 0; u < JC; ++u) {
                    int j = j0 + u;
                    if constexpr (PACKED) {
                        ar[u]  = CB1[j];
                        az[u]  = CB1[HID + j];
                        ain[u] = CB1[2 * HID + j];
                        ahn[u] = CB1[3 * HID + j];
                    } else {
                        ar[u]  = bih1[j] + bhh1[j];
                        az[u]  = bih1[HID + j] + bhh1[HID + j];
                        ain[u] = bih1[2 * HID + j];
                        ahn[u] = bhh1[2 * HID + j];
                    }
                }
                if (t > 0) {
                    for (int k = 0; k < HID; ++k) {
                        const float h1k = h1s[k][b];
                        const float h2k = h2s[k][b];
                        if constexpr (PACKED) {
                            const float* w = P1 + (chunkid * HID + k) * 30;
                            #pragma unroll
                            for (int u = 0; u < JC; ++u) {
                                ar[u]  = fmaf(h1k, w[u],          ar[u]);
                                az[u]  = fmaf(h1k, w[JC + u],     az[u]);
                                ain[u] = fmaf(h1k, w[2 * JC + u], ain[u]);
                                ar[u]  = fmaf(h2k, w[3 * JC + u], ar[u]);
                                az[u]  = fmaf(h2k, w[4 * JC + u], az[u]);
                                ahn[u] = fmaf(h2k, w[5 * JC + u], ahn[u]);
                            }
                        } else {
                            #pragma unroll
                            for (int u = 0; u < JC; ++u) {
                                int j = j0 + u;
                                ar[u]  = fmaf(h1k, P1[j * HID + k],              ar[u]);
                                az[u]  = fmaf(h1k, P1[(HID + j) * HID + k],      az[u]);
                                ain[u] = fmaf(h1k, P1[(2 * HID + j) * HID + k],  ain[u]);
                                ar[u]  = fmaf(h2k, P1b[j * HID + k],             ar[u]);
                                az[u]  = fmaf(h2k, P1b[(HID + j) * HID + k],     az[u]);
                                ahn[u] = fmaf(h2k, P1b[(2 * HID + j) * HID + k], ahn[u]);
                            }
                        }
                    }
                } else {
                    // t == 0: h2 == 0, only the ih matmul contributes
                    for (int k = 0; k < HID; ++k) {
                        const float h1k = h1s[k][b];
                        if constexpr (PACKED) {
                            const float* w = P1 + (chunkid * HID + k) * 30;
                            #pragma unroll
                            for (int u = 0; u < JC; ++u) {
                                ar[u]  = fmaf(h1k, w[u],          ar[u]);
                                az[u]  = fmaf(h1k, w[JC + u],     az[u]);
                                ain[u] = fmaf(h1k, w[2 * JC + u], ain[u]);
                            }
                        } else {
                            #pragma unroll
                            for (int u = 0; u < JC; ++u) {
                                int j = j0 + u;
                                ar[u]  = fmaf(h1k, P1[j * HID + k],             ar[u]);
                                az[u]  = fmaf(h1k, P1[(HID + j) * HID + k],     az[u]);
                                ain[u] = fmaf(h1k, P1[(2 * HID + j) * HID + k], ain[u]);
                            }
                        }
                    }
                }
                #pragma unroll
                for (int u = 0; u < JC; ++u) {
                    float r = sigm(ar[u]);
                    float z = sigm(az[u]);
                    float n = tanh_fast(fmaf(r, ahn[u], ain[u]));
                    float hold = (t > 0) ? h2s[j0 + u][b] : 0.0f;
                    hnew[c * JC + u] = fmaf(z, hold - n, n);
                }
            }
            __syncthreads();
            #pragma unroll
            for (int u = 0; u < JPER; ++u) h2s[jbase + u][b] = hnew[u];
            __syncthreads();
        }

        // output projection: ret = h2(t=9) . Wlin + blin
        if (q == 0) {
            float acc = blin[0];
            for (int k = 0; k < HID; ++k)
                acc = fmaf(h2s[k][b], Wlin[k], acc);
            out[(blockStart + b) * NOUT + it] = acc;
            rets[it][b] = acc;
        }
        __syncthreads();
    }
}

extern "C" void kernel_launch(void* const* d_in, const int* in_sizes, int n_in,
                              void* d_out, int out_size, void* d_ws, size_t ws_size,
                              hipStream_t stream) {
    const float* x    = (const float*)d_in[0];
    const float* Wih0 = (const float*)d_in[1];
    const float* Whh0 = (const float*)d_in[2];
    const float* bih0 = (const float*)d_in[3];
    const float* bhh0 = (const float*)d_in[4];
    const float* Wih1 = (const float*)d_in[5];
    const float* Whh1 = (const float*)d_in[6];
    const float* bih1 = (const float*)d_in[7];
    const float* bhh1 = (const float*)d_in[8];
    const float* Wlin = (const float*)d_in[9];
    const float* blin = (const float*)d_in[10];
    float* out = (float*)d_out;

    const int B = in_sizes[0] / SEQT;
    const int nblocks = B / BTILE;

    const size_t packBytes = (size_t)(P0_FLOATS + P1_FLOATS + CB_FLOATS) * sizeof(float);
    if (ws_size >= packBytes) {
        float* ws = (float*)d_ws;
        prep_kernel<<<90, 256, 0, stream>>>(Whh0, Wih1, Whh1,
                                            bih0, bhh0, bih1, bhh1, ws);
        gru_main<true><<<nblocks, NTHR, 0, stream>>>(
            x, Wih0, bih0, bhh0, bih1, bhh1, Wlin, blin,
            ws, ws + P0_FLOATS, ws + P0_FLOATS + P1_FLOATS, out);
    } else {
        gru_main<false><<<nblocks, NTHR, 0, stream>>>(
            x, Wih0, bih0, bhh0, bih1, bhh1, Wlin, blin,
            Whh0, Wih1, Whh1, out);
    }
}